// Round 15
// baseline (83.822 us; speedup 1.0000x reference)
//
#include <hip/hip_runtime.h>
#include <stdint.h>

#define K_DIM 4096
#define KW 1024          // packed words per m-row
#define M_DIM 11008
#define B_DIM 16
#define GROUP_ROWS 2752  // M / 4 groups

typedef int v4i __attribute__((ext_vector_type(4)));

// spread low byte p (4x 2-bit fields) into 4 bytes: {p&3,(p>>2)&3,(p>>4)&3,(p>>6)&3}
__device__ __forceinline__ int spread2(int p) {
    int t = p | (p << 12);
    return (t & 0x00030003) | (((t >> 2) & 0x00030003) << 8);
}

// ---------------- kernel 1: per-row activation quantization (R8 verbatim) ----------------
__global__ __launch_bounds__(1024) void quant_k(const float* __restrict__ in,
                                                int* __restrict__ qg,
                                                int* __restrict__ sumq,
                                                float* __restrict__ invs) {
    const int b = blockIdx.x, t = threadIdx.x;
    const int lane = t & 63, wid = t >> 6;

    float4 v = ((const float4*)(in + (size_t)b * K_DIM))[t];
    float mx = fmaxf(fmaxf(fabsf(v.x), fabsf(v.y)), fmaxf(fabsf(v.z), fabsf(v.w)));
#pragma unroll
    for (int s = 1; s < 64; s <<= 1) mx = fmaxf(mx, __shfl_xor(mx, s, 64));

    __shared__ float wmax[16];
    __shared__ int wsum[16];
    if (lane == 0) wmax[wid] = mx;
    __syncthreads();
    float bm = wmax[0];
#pragma unroll
    for (int i = 1; i < 16; ++i) bm = fmaxf(bm, wmax[i]);
    const float sc = 127.f / fmaxf(bm, 1e-5f);

    float xs[4] = {v.x, v.y, v.z, v.w};
    int w = 0, ss = 0;
#pragma unroll
    for (int j = 0; j < 4; ++j) {
        int q = (int)rintf(xs[j] * sc);
        q = q > 127 ? 127 : (q < -128 ? -128 : q);
        ss += q;
        w |= (q & 255) << (8 * j);
    }
    qg[b * KW + t] = w;

#pragma unroll
    for (int s = 1; s < 64; s <<= 1) ss += __shfl_xor(ss, s, 64);
    if (lane == 0) wsum[wid] = ss;
    __syncthreads();
    if (t == 0) {
        int tot = 0;
#pragma unroll
        for (int i = 0; i < 16; ++i) tot += wsum[i];
        sumq[b] = tot;
        invs[b] = fmaxf(bm, 1e-5f) / 127.f;
    }
}

// ---------------- A: R8 gemm x4 reps (correct output; acc 4x -> exact >>2) ----------------
__global__ __launch_bounds__(256, 2) void gemm_A(const int* __restrict__ wp,
                                                 const int* __restrict__ qg,
                                                 const int* __restrict__ sumq,
                                                 const float* __restrict__ invs,
                                                 const float* __restrict__ wscale,
                                                 float* __restrict__ out) {
    __shared__ v4i wbuf[4 * 1024];  // 64 KB
    __shared__ int red[4 * 64 * 4]; // 4 KB
    const int t = threadIdx.x, lane = t & 63, wid = t >> 6;
    const int m0 = blockIdx.x * 16;
    const int lrow = lane & 15;
    const int lgrp = lane >> 4;

    v4i qr[16];
#pragma unroll
    for (int s = 0; s < 16; ++s)
        qr[s] = *(const v4i*)(qg + lrow * KW + wid * 256 + s * 16 + lgrp * 4);

    v4i acc = {0, 0, 0, 0};
    for (int rep = 0; rep < 4; ++rep) {
        int off = 0;
        asm volatile("" : "+v"(off));   // opaque zero: blocks cross-rep load CSE
        v4i wst[16];
#pragma unroll
        for (int c = 0; c < 4; ++c)
#pragma unroll
            for (int i = 0; i < 4; ++i) {
                const int row = i * 4 + lgrp;
                wst[c * 4 + i] = __builtin_nontemporal_load(
                    (const v4i*)(wp + (size_t)(m0 + row) * KW + wid * 256 + c * 64 + lrow * 4 + off));
            }
#pragma unroll
        for (int c = 0; c < 4; ++c) {
#pragma unroll
            for (int i = 0; i < 4; ++i) {
                const int row = i * 4 + lgrp;
                wbuf[wid * 1024 + c * 256 + row * 16 + (lrow ^ (row & 7))] = wst[c * 4 + i];
            }
            asm volatile("s_waitcnt lgkmcnt(0)" ::: "memory");
#pragma unroll
            for (int sp = 0; sp < 4; ++sp) {
                v4i wv = wbuf[wid * 1024 + c * 256 + lrow * 16 + ((sp * 4 + lgrp) ^ (lrow & 7))];
                v4i bb;
                bb[0] = spread2(wv[0]); bb[1] = spread2(wv[1]);
                bb[2] = spread2(wv[2]); bb[3] = spread2(wv[3]);
                acc = __builtin_amdgcn_mfma_i32_16x16x64_i8(qr[c * 4 + sp], bb, acc, 0, 0, 0);
            }
        }
    }

    *(v4i*)(red + (wid * 64 + lane) * 4) = acc;
    __syncthreads();

    const int b = t >> 4, m = t & 15;
    const int src_lane = ((b >> 2) << 4) | m;
    const int reg = b & 3;
    int sum = red[(0 * 64 + src_lane) * 4 + reg] + red[(1 * 64 + src_lane) * 4 + reg] +
              red[(2 * 64 + src_lane) * 4 + reg] + red[(3 * 64 + src_lane) * 4 + reg];
    sum >>= 2;  // exact: sum is 4x the true value
    const float val = (float)(sum - sumq[b]) * invs[b] * wscale[m0 / GROUP_ROWS];
    out[(size_t)b * M_DIM + m0 + m] = val;
}

// ---------------- C: A minus MFMA (loads + LDS round-trip + spread2, xor sink) ----------------
__global__ __launch_bounds__(256, 2) void gemm_C(const int* __restrict__ wp,
                                                 const int* __restrict__ qg,
                                                 int* __restrict__ sink) {
    __shared__ v4i wbuf[4 * 1024];
    __shared__ int red[4 * 64 * 4];
    const int t = threadIdx.x, lane = t & 63, wid = t >> 6;
    const int m0 = blockIdx.x * 16;
    const int lrow = lane & 15;
    const int lgrp = lane >> 4;

    v4i qr[16];
#pragma unroll
    for (int s = 0; s < 16; ++s)
        qr[s] = *(const v4i*)(qg + lrow * KW + wid * 256 + s * 16 + lgrp * 4);
    int s0 = 0;
#pragma unroll
    for (int k = 0; k < 16; ++k) s0 ^= qr[k][0] ^ qr[k][1] ^ qr[k][2] ^ qr[k][3];

    for (int rep = 0; rep < 4; ++rep) {
        int off = 0;
        asm volatile("" : "+v"(off));
        v4i wst[16];
#pragma unroll
        for (int c = 0; c < 4; ++c)
#pragma unroll
            for (int i = 0; i < 4; ++i) {
                const int row = i * 4 + lgrp;
                wst[c * 4 + i] = __builtin_nontemporal_load(
                    (const v4i*)(wp + (size_t)(m0 + row) * KW + wid * 256 + c * 64 + lrow * 4 + off));
            }
#pragma unroll
        for (int c = 0; c < 4; ++c) {
#pragma unroll
            for (int i = 0; i < 4; ++i) {
                const int row = i * 4 + lgrp;
                wbuf[wid * 1024 + c * 256 + row * 16 + (lrow ^ (row & 7))] = wst[c * 4 + i];
            }
            asm volatile("s_waitcnt lgkmcnt(0)" ::: "memory");
#pragma unroll
            for (int sp = 0; sp < 4; ++sp) {
                v4i wv = wbuf[wid * 1024 + c * 256 + lrow * 16 + ((sp * 4 + lgrp) ^ (lrow & 7))];
                s0 ^= spread2(wv[0]) ^ spread2(wv[1]) ^ spread2(wv[2]) ^ spread2(wv[3]);
            }
        }
    }
    red[t] = s0;           // keep red allocated (same LDS footprint as A)
    __syncthreads();
    sink[(size_t)blockIdx.x * 256 + t] = red[t];
}

// ---------------- D: A's load burst only (no LDS consume; same LDS footprint) ----------------
__global__ __launch_bounds__(256, 2) void gemm_D(const int* __restrict__ wp,
                                                 int* __restrict__ sink) {
    __shared__ v4i wbuf[4 * 1024];
    __shared__ int red[4 * 64 * 4];
    const int t = threadIdx.x, lane = t & 63, wid = t >> 6;
    const int m0 = blockIdx.x * 16;
    const int lrow = lane & 15;
    const int lgrp = lane >> 4;

    int s0 = 0;
    for (int rep = 0; rep < 8; ++rep) {
        int off = 0;
        asm volatile("" : "+v"(off));
        v4i w[16];
#pragma unroll
        for (int c = 0; c < 4; ++c)
#pragma unroll
            for (int i = 0; i < 4; ++i) {
                const int row = i * 4 + lgrp;
                w[c * 4 + i] = __builtin_nontemporal_load(
                    (const v4i*)(wp + (size_t)(m0 + row) * KW + wid * 256 + c * 64 + lrow * 4 + off));
            }
#pragma unroll
        for (int k = 0; k < 16; ++k) s0 ^= w[k][0] ^ w[k][1] ^ w[k][2] ^ w[k][3];
    }
    // touch both shared arrays so the allocation (-> 2 blocks/CU like A) is kept
    ((int*)wbuf)[t] = s0;
    red[t] = s0;
    __syncthreads();
    sink[(size_t)blockIdx.x * 256 + t] = ((int*)wbuf)[t] ^ red[t] ^ s0;
}

extern "C" void kernel_launch(void* const* d_in, const int* in_sizes, int n_in,
                              void* d_out, int out_size, void* d_ws, size_t ws_size,
                              hipStream_t stream) {
    const float* inp    = (const float*)d_in[0];
    const int*   wp     = (const int*)d_in[1];
    const float* wscale = (const float*)d_in[2];
    float* out = (float*)d_out;

    int*   qg    = (int*)d_ws;               // 64 KB
    int*   sumq  = qg + B_DIM * KW;          // 16 ints
    float* invs  = (float*)(sumq + B_DIM);   // 16 floats
    int*   sinkC = (int*)d_ws + (1 << 20);   // 704 KB @ +4 MB
    int*   sinkD = (int*)d_ws + (2 << 20);   // 704 KB @ +8 MB

    quant_k<<<dim3(B_DIM), dim3(1024), 0, stream>>>(inp, qg, sumq, invs);
    gemm_A<<<dim3(M_DIM / 16), dim3(256), 0, stream>>>(wp, qg, sumq, invs, wscale, out);
    gemm_C<<<dim3(M_DIM / 16), dim3(256), 0, stream>>>(wp, qg, sinkC);
    gemm_D<<<dim3(M_DIM / 16), dim3(256), 0, stream>>>(wp, sinkD);
}